// Round 17
// baseline (110.720 us; speedup 1.0000x reference)
//
#include <hip/hip_runtime.h>
#include <stdint.h>

// VectorQuantizer — f32 I/O confirmed. d_in[0]=z [16384,64], d_in[1]=e [8192,64];
// d_out f32: [z_q 16384*64][idx-as-float 16384]. d_ws = 256MB (r16 fill evidence).
//
// FROZEN exact numerics (eval path only):
//   sz,se: scalar pairwise-8; c: 4 lanes (k mod 4), mul/add separately rounded,
//   16-chunks ascending, reversed sub-blocks (+12,+8,+4,+0), hadd (q0+q1)+(q2+q3);
//   A=fl(sz+se); d=fl(A-2c); argmin strict-<, first (smallest) index wins.
//
// Round-17: eval v9. r16 was z-DELIVERY-LATENCY-BOUND: 128 z-dwords/pass via
// batched s_loads (SGPR=112 can't hold them) = ~7.5K exposed cyc/pass (Occ 18%,
// 80% stall). Fix: block-cooperative z staging — per pass, 128 threads stage the
// 8 items' z-rows (2KB) coalesced into LDS (one vmcnt wait, shared by 4 waves);
// ids+sz double-buffered and prefetched one pass ahead (cand->sz chain hidden
// under compute). Inner loop: zero VMEM/SMEM — z via uniform ds_read_b128
// broadcast, e via stride-68 b128 (conflict-optimal). Early-exit before staging.

#define NROWS 16384
#define NE    8192
#define D     64
#define BN    128
#define NCH   (NE / BN)     // 64
#define BAND  1.25e-4f
#define CAND_CAP 16384
#define EVG   16            // groups per chunk; block = 4 waves, 8 items/pass
#define ELS   68            // LDS row stride (floats): 272B, 16B-aligned

typedef __attribute__((ext_vector_type(8))) short short8;
typedef __attribute__((ext_vector_type(4))) float f32x4;

__device__ __forceinline__ uint32_t bf16rn(float f) {
    union { float f; uint32_t u; } c; c.f = f;
    return (c.u + 0x7FFFu + ((c.u >> 16) & 1u)) >> 16;
}
__device__ __forceinline__ uint32_t pk2(float lo, float hi) {
    return bf16rn(lo) | (bf16rn(hi) << 16);
}

// ---------- phase 0: fused convert + coalesced exact prep (verified) ----------
__global__ __launch_bounds__(256)
void vq_convert_prep(const float* __restrict__ z, const float* __restrict__ e,
                     uint32_t* __restrict__ zb, uint32_t* __restrict__ eb,
                     float* __restrict__ sz_arr, float* __restrict__ se_arr)
{
    if (blockIdx.x < 768) {
        const int i = blockIdx.x * 256 + threadIdx.x;
        const int nz = NROWS * D / 8;
        const int ne = NE * D / 8;
        if (i < nz) {
            const float4 a = ((const float4*)z)[i * 2];
            const float4 b = ((const float4*)z)[i * 2 + 1];
            uint4 o; o.x = pk2(a.x, a.y); o.y = pk2(a.z, a.w);
            o.z = pk2(b.x, b.y); o.w = pk2(b.z, b.w);
            ((uint4*)zb)[i] = o;
        } else if (i < nz + ne) {
            const int k = i - nz;
            const float4 a = ((const float4*)e)[k * 2];
            const float4 b = ((const float4*)e)[k * 2 + 1];
            uint4 o; o.x = pk2(a.x, a.y); o.y = pk2(a.z, a.w);
            o.z = pk2(b.x, b.y); o.w = pk2(b.z, b.w);
            ((uint4*)eb)[k] = o;
        }
    } else {
        const int pb   = blockIdx.x - 768;
        const int wave = threadIdx.x >> 6, lane = threadIdx.x & 63;
        const int g    = lane & 7;
        const int grow = pb * 32 + wave * 8 + (lane >> 3);
        const float* src = (grow < NROWS) ? z + (size_t)grow * D
                                          : e + (size_t)(grow - NROWS) * D;
        float acc = 0.f;
        #pragma unroll
        for (int i = 0; i < 8; ++i) {
            const float x = src[i * 8 + g];
            acc = __fadd_rn(acc, __fmul_rn(x, x));
        }
        const float s1 = __fadd_rn(acc, __shfl_xor(acc, 1, 64));
        const float s2 = __fadd_rn(s1,  __shfl_xor(s1, 2, 64));
        const float s4 = __fadd_rn(s2,  __shfl_xor(s2, 4, 64));
        if (g == 0) {
            if (grow < NROWS) sz_arr[grow] = s4;
            else              se_arr[grow - NROWS] = s4;
        }
    }
}

// ---------- phase 1: MFMA GEMM + per-(row,chunk) max (verified, unchanged) ----------
__global__ __launch_bounds__(256)
void vq_scan_mfma(const uint16_t* __restrict__ zb, const uint16_t* __restrict__ eb,
                  float* __restrict__ cmax)
{
    __shared__ uint16_t elds[BN][72];
    __shared__ float    rmld[4][64][20];

    const int tid  = threadIdx.x;
    const int lane = tid & 63, w = tid >> 6;
    const int mb   = blockIdx.x >> 5;
    const int jb   = blockIdx.x & 31;
    const int row0 = mb * 256 + w * 64;
    const int l15  = lane & 15, l4 = lane >> 4;

    short8 af[4][2];
    #pragma unroll
    for (int m = 0; m < 4; ++m)
        #pragma unroll
        for (int h = 0; h < 2; ++h)
            af[m][h] = *(const short8*)(zb + (size_t)(row0 + m * 16 + l15) * D + h * 32 + l4 * 8);

    const f32x4 z4 = {0.f, 0.f, 0.f, 0.f};

    #pragma unroll 1
    for (int c = 0; c < 2; ++c) {
        const int j0 = jb * 256 + c * BN;
        {
            const int srow = tid >> 1, shalf = tid & 1;
            const uint16_t* sp = eb + (size_t)(j0 + srow) * D + shalf * 32;
            uint16_t* dp = &elds[srow][shalf * 32];
            #pragma unroll
            for (int q = 0; q < 4; ++q)
                *(short8*)(dp + q * 8) = *(const short8*)(sp + q * 8);
        }
        __syncthreads();

        f32x4 rm[4];
        #pragma unroll
        for (int m = 0; m < 4; ++m) rm[m] = {-3.0e38f, -3.0e38f, -3.0e38f, -3.0e38f};

        #pragma unroll 1
        for (int n = 0; n < 8; ++n) {
            const uint16_t* bp = &elds[n * 16 + l15][l4 * 8];
            const short8 b0 = *(const short8*)(bp);
            const short8 b1 = *(const short8*)(bp + 32);
            #pragma unroll
            for (int m = 0; m < 4; ++m) {
                f32x4 acc = __builtin_amdgcn_mfma_f32_16x16x32_bf16(af[m][0], b0, z4, 0, 0, 0);
                acc = __builtin_amdgcn_mfma_f32_16x16x32_bf16(af[m][1], b1, acc, 0, 0, 0);
                #pragma unroll
                for (int r = 0; r < 4; ++r) rm[m][r] = fmaxf(rm[m][r], acc[r]);
            }
        }

        #pragma unroll
        for (int m = 0; m < 4; ++m)
            *(f32x4*)&rmld[w][lane][m * 4] = rm[m];
        const int r  = lane;
        const int mm = r >> 4, rg = r & 3, lg = ((r & 15) >> 2) * 16;
        float v = rmld[w][lg][mm * 4 + rg];
        #pragma unroll
        for (int i = 1; i < 16; ++i) v = fmaxf(v, rmld[w][lg + i][mm * 4 + rg]);
        cmax[(size_t)(row0 + r) * NCH + (jb * 2 + c)] = v;
        __syncthreads();
    }
}

// ---------- phase 2a: band-select -> per-row bitmask (no atomics) ----------
__global__ __launch_bounds__(256)
void vq_select_mask(const float* __restrict__ cmax,
                    unsigned long long* __restrict__ mask,
                    unsigned long long* __restrict__ packed)
{
    const int lane = threadIdx.x & 63, w = threadIdx.x >> 6;
    const int row = blockIdx.x * 4 + w;

    const float ci = cmax[(size_t)row * NCH + lane];   // lane = chunk
    float cm = ci;
    #pragma unroll
    for (int o = 1; o < 64; o <<= 1) cm = fmaxf(cm, __shfl_xor(cm, o, 64));
    const unsigned long long m = __ballot(ci >= cm - BAND);
    if (lane == 0) { mask[row] = m; packed[row] = 0xFFFFFFFFFFFFFFFFull; }
}

// ---------- phase 2b: compaction (barrier-free, LDS atomic, unordered) ----------
__global__ __launch_bounds__(256)
void vq_compact(const unsigned long long* __restrict__ mask,
                int* __restrict__ cand, unsigned int* __restrict__ counts)
{
    __shared__ unsigned int cnt_lds;
    const int ch = blockIdx.x;
    const int t = threadIdx.x, lane = t & 63;
    if (t == 0) cnt_lds = 0;
    __syncthreads();

    #pragma unroll 1
    for (int r0 = 0; r0 < NROWS; r0 += 256) {
        const int row = r0 + t;
        const bool hit = (mask[row] >> ch) & 1ull;
        const unsigned long long b = __ballot(hit);
        unsigned int base = 0;
        if (lane == 0 && b) base = atomicAdd(&cnt_lds, (unsigned int)__popcll(b));
        base = (unsigned int)__shfl((int)base, 0, 64);
        if (hit) {
            const unsigned int rank = (unsigned int)__popcll(b & ((1ull << lane) - 1ull));
            cand[(size_t)ch * CAND_CAP + base + rank] = row;
        }
    }
    __syncthreads();
    if (t == 0) counts[ch] = cnt_lds;
}

// ---------- phase 2c: eval v9 — block-staged z, double-buffered ids ----------
__global__ __launch_bounds__(256)
void vq_eval(const float* __restrict__ z, const float* __restrict__ e,
             const float* __restrict__ sz_arr, const float* __restrict__ se_arr,
             const unsigned int* __restrict__ counts, const int* __restrict__ cand,
             unsigned long long* __restrict__ packed)
{
    __shared__ float el[BN * ELS];       // 34 KB e-chunk, stride-68 b128-optimal
    __shared__ float zl[8][ELS];         // 2 KB: this pass's 8 z-rows
    __shared__ int   idsb[2][8];
    __shared__ float szb[2][8];

    const int ch  = blockIdx.x;          // 0..63
    const int grp = blockIdx.y;          // 0..EVG-1
    const int t   = threadIdx.x, lane = t & 63, w = t >> 6;

    const unsigned int cnt = counts[ch];
    const int base0 = grp * 8;
    if ((unsigned int)base0 >= cnt) return;                  // uniform: whole block exits
    const int npass = ((int)cnt - base0 - 1) / 128 + 1;      // stride 128 items/pass

    {   // stage e-chunk: coalesced float4 reads -> b128 LDS writes
        const float4* src4 = (const float4*)(e + (size_t)ch * BN * D);
        #pragma unroll
        for (int v = t; v < BN * D / 4; v += 256) {
            const int row = v >> 4, c4 = (v & 15) << 2;
            *(float4*)&el[row * ELS + c4] = src4[v];
        }
    }
    if (t < 8) {   // prologue: ids + sz for pass 0
        unsigned int it = (unsigned int)(base0 + t);
        if (it >= cnt) it = cnt - 1;                         // dup tail: idempotent
        const int id = cand[(size_t)ch * CAND_CAP + it];
        idsb[0][t] = id;
        szb[0][t] = sz_arr[id];
    }
    __syncthreads();

    const int jbase = ch * BN;
    const float* e0 = &el[lane * ELS];            // j = jbase + lane
    const float* e1 = &el[(lane + 64) * ELS];     // j = jbase + 64 + lane
    const float se0 = se_arr[jbase + lane];
    const float se1 = se_arr[jbase + 64 + lane];

    #pragma unroll 1
    for (int k = 0; k < npass; ++k) {
        const int cur = k & 1, nxt = cur ^ 1;
        if (t < 128) {   // z-stage: 8 rows x 16 float4, coalesced, one vmcnt wait
            const int slot = t >> 4, c4 = (t & 15) << 2;
            const int rid = idsb[cur][slot];
            *(float4*)&zl[slot][c4] = *(const float4*)(z + (size_t)rid * D + c4);
        }
        if (t < 8 && k + 1 < npass) {   // prefetch next pass's ids+sz (hidden)
            unsigned int it = (unsigned int)(base0 + (k + 1) * 128 + t);
            if (it >= cnt) it = cnt - 1;
            const int id = cand[(size_t)ch * CAND_CAP + it];
            idsb[nxt][t] = id;
            szb[nxt][t] = sz_arr[id];
        }
        __syncthreads();   // zl + next ids ready

        const int s0 = base0 + k * 128 + w * 2;
        if ((unsigned int)s0 < cnt) {
            const int sl0 = w * 2;
            const int sl1 = ((unsigned int)(s0 + 1) < cnt) ? sl0 + 1 : sl0;  // dup: idempotent
            const int row0 = idsb[cur][sl0];
            const int row1 = idsb[cur][sl1];
            const float sz0 = szb[cur][sl0];
            const float sz1 = szb[cur][sl1];
            const float* zp0 = &zl[sl0][0];
            const float* zp1 = &zl[sl1][0];

            // frozen order per accumulator set: cc ascending; granules +12,+8,+4,+0
            float a00 = 0.f, a01 = 0.f, a02 = 0.f, a03 = 0.f;   // row0 x j=lane
            float a10 = 0.f, a11 = 0.f, a12 = 0.f, a13 = 0.f;   // row0 x j=lane+64
            float b00 = 0.f, b01 = 0.f, b02 = 0.f, b03 = 0.f;   // row1 x j=lane
            float b10 = 0.f, b11 = 0.f, b12 = 0.f, b13 = 0.f;   // row1 x j=lane+64
            #pragma unroll
            for (int cc = 0; cc < 4; ++cc) {
                #pragma unroll
                for (int sb = 3; sb >= 0; --sb) {
                    const int b = cc * 16 + sb * 4;
                    const float4 ef0 = *(const float4*)&e0[b];    // ds_read_b128
                    const float4 ef1 = *(const float4*)&e1[b];    // ds_read_b128
                    const float4 zv0 = *(const float4*)&zp0[b];   // b128 broadcast
                    const float4 zv1 = *(const float4*)&zp1[b];   // b128 broadcast
                    a00 = __fadd_rn(a00, __fmul_rn(zv0.x, ef0.x));
                    a01 = __fadd_rn(a01, __fmul_rn(zv0.y, ef0.y));
                    a02 = __fadd_rn(a02, __fmul_rn(zv0.z, ef0.z));
                    a03 = __fadd_rn(a03, __fmul_rn(zv0.w, ef0.w));
                    a10 = __fadd_rn(a10, __fmul_rn(zv0.x, ef1.x));
                    a11 = __fadd_rn(a11, __fmul_rn(zv0.y, ef1.y));
                    a12 = __fadd_rn(a12, __fmul_rn(zv0.z, ef1.z));
                    a13 = __fadd_rn(a13, __fmul_rn(zv0.w, ef1.w));
                    b00 = __fadd_rn(b00, __fmul_rn(zv1.x, ef0.x));
                    b01 = __fadd_rn(b01, __fmul_rn(zv1.y, ef0.y));
                    b02 = __fadd_rn(b02, __fmul_rn(zv1.z, ef0.z));
                    b03 = __fadd_rn(b03, __fmul_rn(zv1.w, ef0.w));
                    b10 = __fadd_rn(b10, __fmul_rn(zv1.x, ef1.x));
                    b11 = __fadd_rn(b11, __fmul_rn(zv1.y, ef1.y));
                    b12 = __fadd_rn(b12, __fmul_rn(zv1.z, ef1.z));
                    b13 = __fadd_rn(b13, __fmul_rn(zv1.w, ef1.w));
                }
            }
            // row0
            {
                const float c0 = __fadd_rn(__fadd_rn(a00, a01), __fadd_rn(a02, a03));
                const float c1 = __fadd_rn(__fadd_rn(a10, a11), __fadd_rn(a12, a13));
                const float A0 = __fadd_rn(sz0, se0);
                const float A1 = __fadd_rn(sz0, se1);
                float d  = __fsub_rn(A0, __fadd_rn(c0, c0));
                int   bj = jbase + lane;
                const float d1 = __fsub_rn(A1, __fadd_rn(c1, c1));
                if (d1 < d) { d = d1; bj = jbase + 64 + lane; }   // j0<j1: tie keeps j0
                #pragma unroll
                for (int o = 1; o < 64; o <<= 1) {
                    const float od = __shfl_xor(d, o, 64);
                    const int   oj = __shfl_xor(bj, o, 64);
                    if (od < d || (od == d && oj < bj)) { d = od; bj = oj; }
                }
                if (lane == 0) {
                    const unsigned long long key =
                        ((unsigned long long)__float_as_uint(d) << 32) | (unsigned int)bj;
                    atomicMin(packed + row0, key);   // d>0 -> monotone; deterministic
                }
            }
            // row1 (equals row0 on dup tail: identical key, idempotent)
            {
                const float c0 = __fadd_rn(__fadd_rn(b00, b01), __fadd_rn(b02, b03));
                const float c1 = __fadd_rn(__fadd_rn(b10, b11), __fadd_rn(b12, b13));
                const float A0 = __fadd_rn(sz1, se0);
                const float A1 = __fadd_rn(sz1, se1);
                float d  = __fsub_rn(A0, __fadd_rn(c0, c0));
                int   bj = jbase + lane;
                const float d1 = __fsub_rn(A1, __fadd_rn(c1, c1));
                if (d1 < d) { d = d1; bj = jbase + 64 + lane; }
                #pragma unroll
                for (int o = 1; o < 64; o <<= 1) {
                    const float od = __shfl_xor(d, o, 64);
                    const int   oj = __shfl_xor(bj, o, 64);
                    if (od < d || (od == d && oj < bj)) { d = od; bj = oj; }
                }
                if (lane == 0) {
                    const unsigned long long key =
                        ((unsigned long long)__float_as_uint(d) << 32) | (unsigned int)bj;
                    atomicMin(packed + row1, key);
                }
            }
        }
        __syncthreads();   // compute done before next z-stage overwrites zl
    }
}

// ---------- phase 3: z_q + idx from packed ----------
__global__ __launch_bounds__(256)
void vq_zq(const float* __restrict__ z, const float* __restrict__ e,
           const unsigned long long* __restrict__ packed, float* __restrict__ out)
{
    const size_t m = (size_t)blockIdx.x * 256 + threadIdx.x;
    const int r = (int)(m >> 6), k = (int)(m & 63);
    const int sel = (int)(packed[r] & 0xFFFFFFFFull);
    const float zv = z[m];
    const float ev = e[(size_t)sel * D + k];
    out[m] = __fadd_rn(zv, __fsub_rn(ev, zv));
    if (k == 0) out[(size_t)NROWS * D + r] = (float)sel;
}

extern "C" void kernel_launch(void* const* d_in, const int* in_sizes, int n_in,
                              void* d_out, int out_size, void* d_ws, size_t ws_size,
                              hipStream_t stream)
{
    const float* z = (const float*)d_in[0];
    const float* e = (const float*)d_in[1];
    float* out = (float*)d_out;

    char* ws = (char*)d_ws;
    const size_t MB = 1024 * 1024, KB = 1024;
    uint16_t* zb               = (uint16_t*)(ws);                         // 0..2 MB
    uint16_t* eb               = (uint16_t*)(ws + 2 * MB);                // 2..3 MB
    float* cmaxb               = (float*)(ws + 3 * MB);                   // 3..7 MB
    float* sz_arr              = (float*)(ws + 7 * MB);                   // 64 KB
    float* se_arr              = (float*)(ws + 7 * MB + 64 * KB);         // 32 KB
    unsigned long long* mask   = (unsigned long long*)(ws + 7 * MB + 128 * KB); // 128 KB
    unsigned long long* packed = (unsigned long long*)(ws + 7 * MB + 256 * KB); // 128 KB
    unsigned int* counts       = (unsigned int*)(ws + 7 * MB + 384 * KB); // 256 B
    int* cand                  = (int*)(ws + 8 * MB);                     // 8..12 MB

    vq_convert_prep<<<dim3(1536),            dim3(256), 0, stream>>>(z, e, (uint32_t*)zb, (uint32_t*)eb, sz_arr, se_arr);
    vq_scan_mfma   <<<dim3(2048),            dim3(256), 0, stream>>>(zb, eb, cmaxb);
    vq_select_mask <<<dim3(NROWS / 4),       dim3(256), 0, stream>>>(cmaxb, mask, packed);
    vq_compact     <<<dim3(NCH),             dim3(256), 0, stream>>>(mask, cand, counts);
    vq_eval        <<<dim3(NCH, EVG),        dim3(256), 0, stream>>>(z, e, sz_arr, se_arr, counts, cand, packed);
    vq_zq          <<<dim3(NROWS * D / 256), dim3(256), 0, stream>>>(z, e, packed, out);
}

// Round 18
// 105.654 us; speedup vs baseline: 1.0480x; 1.0480x over previous
//
#include <hip/hip_runtime.h>
#include <stdint.h>

// VectorQuantizer — f32 I/O confirmed. d_in[0]=z [16384,64], d_in[1]=e [8192,64];
// d_out f32: [z_q 16384*64][idx-as-float 16384]. d_ws = 256MB confirmed.
//
// FROZEN exact numerics (eval path only):
//   sz,se: scalar pairwise-8; c: 4 lanes (k mod 4), mul/add separately rounded,
//   16-chunks ascending, reversed sub-blocks (+12,+8,+4,+0), hadd (q0+q1)+(q2+q3);
//   A=fl(sz+se); d=fl(A-2c); argmin strict-<, first (smallest) index wins.
//
// Round-18: eval v10. r13-r17 model closure: eval's invariant ~40-47us was the
// DS-pipe floor — 32+ ds_read_b128 per ITEM (26K items x 64 b128 / 256 CU x
// 12cyc ~ 16-20us + overheads). Fix: (a) 4 items/pass -> e-reads amortized 4x
// (8 b128/item, DS floor ~8us); (b) z via lane-distributed VGPRs (lane holds
// granule lane&15 of item lane>>4; ONE coalesced float4 load/pass) broadcast
// with v_readlane (VALU->SGPR, not DS); (c) no intra-loop barriers (waves
// independent; cand/sz wave-uniform s_loads). 32 fully-static accumulators —
// no 64-float arrays (remat-curse rule). Dup-tail idempotent under atomicMin.

#define NROWS 16384
#define NE    8192
#define D     64
#define BN    128
#define NCH   (NE / BN)     // 64
#define BAND  1.25e-4f
#define CAND_CAP 16384
#define EVG   16            // groups per chunk; block = 4 waves x 4 items = 16 items/pass
#define ELS   68            // LDS row stride (floats): 272B, 16B-aligned, b128-optimal

typedef __attribute__((ext_vector_type(8))) short short8;
typedef __attribute__((ext_vector_type(4))) float f32x4;

__device__ __forceinline__ uint32_t bf16rn(float f) {
    union { float f; uint32_t u; } c; c.f = f;
    return (c.u + 0x7FFFu + ((c.u >> 16) & 1u)) >> 16;
}
__device__ __forceinline__ uint32_t pk2(float lo, float hi) {
    return bf16rn(lo) | (bf16rn(hi) << 16);
}
#define RL(v, l) __uint_as_float(__builtin_amdgcn_readlane(__float_as_uint(v), (l)))

// ---------- phase 0: fused convert + coalesced exact prep (verified) ----------
__global__ __launch_bounds__(256)
void vq_convert_prep(const float* __restrict__ z, const float* __restrict__ e,
                     uint32_t* __restrict__ zb, uint32_t* __restrict__ eb,
                     float* __restrict__ sz_arr, float* __restrict__ se_arr)
{
    if (blockIdx.x < 768) {
        const int i = blockIdx.x * 256 + threadIdx.x;
        const int nz = NROWS * D / 8;
        const int ne = NE * D / 8;
        if (i < nz) {
            const float4 a = ((const float4*)z)[i * 2];
            const float4 b = ((const float4*)z)[i * 2 + 1];
            uint4 o; o.x = pk2(a.x, a.y); o.y = pk2(a.z, a.w);
            o.z = pk2(b.x, b.y); o.w = pk2(b.z, b.w);
            ((uint4*)zb)[i] = o;
        } else if (i < nz + ne) {
            const int k = i - nz;
            const float4 a = ((const float4*)e)[k * 2];
            const float4 b = ((const float4*)e)[k * 2 + 1];
            uint4 o; o.x = pk2(a.x, a.y); o.y = pk2(a.z, a.w);
            o.z = pk2(b.x, b.y); o.w = pk2(b.z, b.w);
            ((uint4*)eb)[k] = o;
        }
    } else {
        const int pb   = blockIdx.x - 768;
        const int wave = threadIdx.x >> 6, lane = threadIdx.x & 63;
        const int g    = lane & 7;
        const int grow = pb * 32 + wave * 8 + (lane >> 3);
        const float* src = (grow < NROWS) ? z + (size_t)grow * D
                                          : e + (size_t)(grow - NROWS) * D;
        float acc = 0.f;
        #pragma unroll
        for (int i = 0; i < 8; ++i) {
            const float x = src[i * 8 + g];
            acc = __fadd_rn(acc, __fmul_rn(x, x));
        }
        const float s1 = __fadd_rn(acc, __shfl_xor(acc, 1, 64));
        const float s2 = __fadd_rn(s1,  __shfl_xor(s1, 2, 64));
        const float s4 = __fadd_rn(s2,  __shfl_xor(s2, 4, 64));
        if (g == 0) {
            if (grow < NROWS) sz_arr[grow] = s4;
            else              se_arr[grow - NROWS] = s4;
        }
    }
}

// ---------- phase 1: MFMA GEMM + per-(row,chunk) max (verified, unchanged) ----------
__global__ __launch_bounds__(256)
void vq_scan_mfma(const uint16_t* __restrict__ zb, const uint16_t* __restrict__ eb,
                  float* __restrict__ cmax)
{
    __shared__ uint16_t elds[BN][72];
    __shared__ float    rmld[4][64][20];

    const int tid  = threadIdx.x;
    const int lane = tid & 63, w = tid >> 6;
    const int mb   = blockIdx.x >> 5;
    const int jb   = blockIdx.x & 31;
    const int row0 = mb * 256 + w * 64;
    const int l15  = lane & 15, l4 = lane >> 4;

    short8 af[4][2];
    #pragma unroll
    for (int m = 0; m < 4; ++m)
        #pragma unroll
        for (int h = 0; h < 2; ++h)
            af[m][h] = *(const short8*)(zb + (size_t)(row0 + m * 16 + l15) * D + h * 32 + l4 * 8);

    const f32x4 z4 = {0.f, 0.f, 0.f, 0.f};

    #pragma unroll 1
    for (int c = 0; c < 2; ++c) {
        const int j0 = jb * 256 + c * BN;
        {
            const int srow = tid >> 1, shalf = tid & 1;
            const uint16_t* sp = eb + (size_t)(j0 + srow) * D + shalf * 32;
            uint16_t* dp = &elds[srow][shalf * 32];
            #pragma unroll
            for (int q = 0; q < 4; ++q)
                *(short8*)(dp + q * 8) = *(const short8*)(sp + q * 8);
        }
        __syncthreads();

        f32x4 rm[4];
        #pragma unroll
        for (int m = 0; m < 4; ++m) rm[m] = {-3.0e38f, -3.0e38f, -3.0e38f, -3.0e38f};

        #pragma unroll 1
        for (int n = 0; n < 8; ++n) {
            const uint16_t* bp = &elds[n * 16 + l15][l4 * 8];
            const short8 b0 = *(const short8*)(bp);
            const short8 b1 = *(const short8*)(bp + 32);
            #pragma unroll
            for (int m = 0; m < 4; ++m) {
                f32x4 acc = __builtin_amdgcn_mfma_f32_16x16x32_bf16(af[m][0], b0, z4, 0, 0, 0);
                acc = __builtin_amdgcn_mfma_f32_16x16x32_bf16(af[m][1], b1, acc, 0, 0, 0);
                #pragma unroll
                for (int r = 0; r < 4; ++r) rm[m][r] = fmaxf(rm[m][r], acc[r]);
            }
        }

        #pragma unroll
        for (int m = 0; m < 4; ++m)
            *(f32x4*)&rmld[w][lane][m * 4] = rm[m];
        const int r  = lane;
        const int mm = r >> 4, rg = r & 3, lg = ((r & 15) >> 2) * 16;
        float v = rmld[w][lg][mm * 4 + rg];
        #pragma unroll
        for (int i = 1; i < 16; ++i) v = fmaxf(v, rmld[w][lg + i][mm * 4 + rg]);
        cmax[(size_t)(row0 + r) * NCH + (jb * 2 + c)] = v;
        __syncthreads();
    }
}

// ---------- phase 2a: band-select -> per-row bitmask (no atomics) ----------
__global__ __launch_bounds__(256)
void vq_select_mask(const float* __restrict__ cmax,
                    unsigned long long* __restrict__ mask,
                    unsigned long long* __restrict__ packed)
{
    const int lane = threadIdx.x & 63, w = threadIdx.x >> 6;
    const int row = blockIdx.x * 4 + w;

    const float ci = cmax[(size_t)row * NCH + lane];   // lane = chunk
    float cm = ci;
    #pragma unroll
    for (int o = 1; o < 64; o <<= 1) cm = fmaxf(cm, __shfl_xor(cm, o, 64));
    const unsigned long long m = __ballot(ci >= cm - BAND);
    if (lane == 0) { mask[row] = m; packed[row] = 0xFFFFFFFFFFFFFFFFull; }
}

// ---------- phase 2b: compaction (barrier-free, LDS atomic, unordered) ----------
__global__ __launch_bounds__(256)
void vq_compact(const unsigned long long* __restrict__ mask,
                int* __restrict__ cand, unsigned int* __restrict__ counts)
{
    __shared__ unsigned int cnt_lds;
    const int ch = blockIdx.x;
    const int t = threadIdx.x, lane = t & 63;
    if (t == 0) cnt_lds = 0;
    __syncthreads();

    #pragma unroll 1
    for (int r0 = 0; r0 < NROWS; r0 += 256) {
        const int row = r0 + t;
        const bool hit = (mask[row] >> ch) & 1ull;
        const unsigned long long b = __ballot(hit);
        unsigned int base = 0;
        if (lane == 0 && b) base = atomicAdd(&cnt_lds, (unsigned int)__popcll(b));
        base = (unsigned int)__shfl((int)base, 0, 64);
        if (hit) {
            const unsigned int rank = (unsigned int)__popcll(b & ((1ull << lane) - 1ull));
            cand[(size_t)ch * CAND_CAP + base + rank] = row;
        }
    }
    __syncthreads();
    if (t == 0) counts[ch] = cnt_lds;
}

// ---------- phase 2c: eval v10 — 4 items/pass, z via readlane, e b128 LDS ----------
__global__ __launch_bounds__(256)
void vq_eval(const float* __restrict__ z, const float* __restrict__ e,
             const float* __restrict__ sz_arr, const float* __restrict__ se_arr,
             const unsigned int* __restrict__ counts, const int* __restrict__ cand,
             unsigned long long* __restrict__ packed)
{
    __shared__ float el[BN * ELS];       // 34 KB e-chunk, stride-68 b128-optimal

    const int ch  = blockIdx.x;          // 0..63
    const int grp = blockIdx.y;          // 0..EVG-1
    const int t   = threadIdx.x, lane = t & 63, w = t >> 6;

    const unsigned int cnt = counts[ch];
    const int base0 = grp * 16;
    if ((unsigned int)base0 >= cnt) return;

    {   // stage e-chunk: coalesced float4 reads -> b128 LDS writes
        const float4* src4 = (const float4*)(e + (size_t)ch * BN * D);
        #pragma unroll
        for (int v = t; v < BN * D / 4; v += 256) {
            const int row = v >> 4, c4 = (v & 15) << 2;
            *(float4*)&el[row * ELS + c4] = src4[v];
        }
    }
    __syncthreads();   // only barrier; el is read-only afterwards

    const int jbase = ch * BN;
    const float* e0 = &el[lane * ELS];            // j = jbase + lane
    const float* e1 = &el[(lane + 64) * ELS];     // j = jbase + 64 + lane
    const float se0 = se_arr[jbase + lane];
    const float se1 = se_arr[jbase + 64 + lane];
    const int gsrc  = lane & 15;                  // granule this lane sources
    const int isrc  = lane >> 4;                  // item this lane sources (0..3)

    for (unsigned int s0 = (unsigned int)(base0 + w * 4); s0 < cnt; s0 += (unsigned int)EVG * 16u) {
        // 4 item slots (tail dups idempotent under atomicMin)
        int rows[4]; float szs[4];
        #pragma unroll
        for (int it = 0; it < 4; ++it) {
            unsigned int si = s0 + it; if (si >= cnt) si = cnt - 1;
            rows[it] = cand[(size_t)ch * CAND_CAP + si];   // uniform -> s_load
            szs[it]  = sz_arr[rows[it]];                   // uniform -> s_load
        }
        // lane-distributed z: lane holds granule gsrc of item isrc (one float4 load)
        const float4 zf = *(const float4*)(z + (size_t)rows[isrc] * D + gsrc * 4);

        // 32 fully-static accumulators: acc[item][jrow][q]
        float acc[4][2][4];
        #pragma unroll
        for (int it = 0; it < 4; ++it)
            #pragma unroll
            for (int jr = 0; jr < 2; ++jr)
                #pragma unroll
                for (int q = 0; q < 4; ++q) acc[it][jr][q] = 0.f;

        // frozen order: cc ascending; granules +12,+8,+4,+0; q_i gets k===i mod 4
        #pragma unroll
        for (int cc = 0; cc < 4; ++cc) {
            #pragma unroll
            for (int sb = 3; sb >= 0; --sb) {
                const int b = cc * 16 + sb * 4;
                const int g = cc * 4 + sb;                 // granule index 0..15
                const float4 ef0 = *(const float4*)&e0[b]; // ds_read_b128
                const float4 ef1 = *(const float4*)&e1[b]; // ds_read_b128
                #pragma unroll
                for (int it = 0; it < 4; ++it) {
                    const int sl = it * 16 + g;            // source lane
                    const float zx = RL(zf.x, sl);         // v_readlane -> SGPR
                    const float zy = RL(zf.y, sl);
                    const float zz = RL(zf.z, sl);
                    const float zw = RL(zf.w, sl);
                    acc[it][0][0] = __fadd_rn(acc[it][0][0], __fmul_rn(zx, ef0.x));
                    acc[it][0][1] = __fadd_rn(acc[it][0][1], __fmul_rn(zy, ef0.y));
                    acc[it][0][2] = __fadd_rn(acc[it][0][2], __fmul_rn(zz, ef0.z));
                    acc[it][0][3] = __fadd_rn(acc[it][0][3], __fmul_rn(zw, ef0.w));
                    acc[it][1][0] = __fadd_rn(acc[it][1][0], __fmul_rn(zx, ef1.x));
                    acc[it][1][1] = __fadd_rn(acc[it][1][1], __fmul_rn(zy, ef1.y));
                    acc[it][1][2] = __fadd_rn(acc[it][1][2], __fmul_rn(zz, ef1.z));
                    acc[it][1][3] = __fadd_rn(acc[it][1][3], __fmul_rn(zw, ef1.w));
                }
            }
        }

        #pragma unroll
        for (int it = 0; it < 4; ++it) {
            const float c0 = __fadd_rn(__fadd_rn(acc[it][0][0], acc[it][0][1]),
                                       __fadd_rn(acc[it][0][2], acc[it][0][3]));
            const float c1 = __fadd_rn(__fadd_rn(acc[it][1][0], acc[it][1][1]),
                                       __fadd_rn(acc[it][1][2], acc[it][1][3]));
            const float A0 = __fadd_rn(szs[it], se0);
            const float A1 = __fadd_rn(szs[it], se1);
            float d  = __fsub_rn(A0, __fadd_rn(c0, c0));
            int   bj = jbase + lane;
            const float d1 = __fsub_rn(A1, __fadd_rn(c1, c1));
            if (d1 < d) { d = d1; bj = jbase + 64 + lane; }   // j0<j1: tie keeps j0
            #pragma unroll
            for (int o = 1; o < 64; o <<= 1) {                // argmin, first-index ties
                const float od = __shfl_xor(d, o, 64);
                const int   oj = __shfl_xor(bj, o, 64);
                if (od < d || (od == d && oj < bj)) { d = od; bj = oj; }
            }
            if (lane == 0) {
                const unsigned long long key =
                    ((unsigned long long)__float_as_uint(d) << 32) | (unsigned int)bj;
                atomicMin(packed + rows[it], key);   // d>0 -> monotone; deterministic
            }
        }
    }
}

// ---------- phase 3: z_q + idx from packed ----------
__global__ __launch_bounds__(256)
void vq_zq(const float* __restrict__ z, const float* __restrict__ e,
           const unsigned long long* __restrict__ packed, float* __restrict__ out)
{
    const size_t m = (size_t)blockIdx.x * 256 + threadIdx.x;
    const int r = (int)(m >> 6), k = (int)(m & 63);
    const int sel = (int)(packed[r] & 0xFFFFFFFFull);
    const float zv = z[m];
    const float ev = e[(size_t)sel * D + k];
    out[m] = __fadd_rn(zv, __fsub_rn(ev, zv));
    if (k == 0) out[(size_t)NROWS * D + r] = (float)sel;
}

extern "C" void kernel_launch(void* const* d_in, const int* in_sizes, int n_in,
                              void* d_out, int out_size, void* d_ws, size_t ws_size,
                              hipStream_t stream)
{
    const float* z = (const float*)d_in[0];
    const float* e = (const float*)d_in[1];
    float* out = (float*)d_out;

    char* ws = (char*)d_ws;
    const size_t MB = 1024 * 1024, KB = 1024;
    uint16_t* zb               = (uint16_t*)(ws);                         // 0..2 MB
    uint16_t* eb               = (uint16_t*)(ws + 2 * MB);                // 2..3 MB
    float* cmaxb               = (float*)(ws + 3 * MB);                   // 3..7 MB
    float* sz_arr              = (float*)(ws + 7 * MB);                   // 64 KB
    float* se_arr              = (float*)(ws + 7 * MB + 64 * KB);         // 32 KB
    unsigned long long* mask   = (unsigned long long*)(ws + 7 * MB + 128 * KB); // 128 KB
    unsigned long long* packed = (unsigned long long*)(ws + 7 * MB + 256 * KB); // 128 KB
    unsigned int* counts       = (unsigned int*)(ws + 7 * MB + 384 * KB); // 256 B
    int* cand                  = (int*)(ws + 8 * MB);                     // 8..12 MB

    vq_convert_prep<<<dim3(1536),            dim3(256), 0, stream>>>(z, e, (uint32_t*)zb, (uint32_t*)eb, sz_arr, se_arr);
    vq_scan_mfma   <<<dim3(2048),            dim3(256), 0, stream>>>(zb, eb, cmaxb);
    vq_select_mask <<<dim3(NROWS / 4),       dim3(256), 0, stream>>>(cmaxb, mask, packed);
    vq_compact     <<<dim3(NCH),             dim3(256), 0, stream>>>(mask, cand, counts);
    vq_eval        <<<dim3(NCH, EVG),        dim3(256), 0, stream>>>(z, e, sz_arr, se_arr, counts, cand, packed);
    vq_zq          <<<dim3(NROWS * D / 256), dim3(256), 0, stream>>>(z, e, packed, out);
}